// Round 3
// baseline (3470.136 us; speedup 1.0000x reference)
//
#include <hip/hip_runtime.h>
#include <math.h>

typedef short bf16x8 __attribute__((ext_vector_type(8)));
typedef float floatx4 __attribute__((ext_vector_type(4)));

__device__ __forceinline__ unsigned short f2bf(float f) {
    unsigned int u = __float_as_uint(f);
    u += 0x7fffu + ((u >> 16) & 1u);   // round-to-nearest-even
    return (unsigned short)(u >> 16);
}
__device__ __forceinline__ float bf2f(unsigned short u) {
    return __uint_as_float(((unsigned int)u) << 16);
}
// async global->LDS, 16B/lane; LDS dest = wave-uniform base + lane*16
__device__ __forceinline__ void async16(void* lds, const void* g) {
    __builtin_amdgcn_global_load_lds((const __attribute__((address_space(1))) unsigned int*)g,
                                     (__attribute__((address_space(3))) unsigned int*)lds,
                                     16, 0, 0);
}

// ---------------- weight convert: all 6 layers, fp32 -> bf16 ----------------
// ushort4-unit slot layout per layer (4194304 units): qkv [0,786432) | out [786432,1048576)
// | w1 [1048576,3145728) | w2 [3145728,4194304)
__global__ __launch_bounds__(256) void conv_all(
        const float* __restrict__ qkv, const float* __restrict__ ow,
        const float* __restrict__ w1, const float* __restrict__ w2,
        unsigned short* __restrict__ dst) {
    size_t i = (size_t)blockIdx.x * 256 + threadIdx.x;   // 25165824 float4 units total
    const float4* s; size_t didx;
    if (i < 4718592) {                       // qkv: 6 x 786432
        size_t layer = i / 786432, off = i % 786432;
        s = (const float4*)qkv + layer * 786432 + off;
        didx = layer * 4194304 + off;
    } else if (i < 6291456) {                // out: 6 x 262144
        size_t j = i - 4718592, layer = j / 262144, off = j % 262144;
        s = (const float4*)ow + layer * 262144 + off;
        didx = layer * 4194304 + 786432 + off;
    } else if (i < 18874368) {               // w1: 6 x 2097152
        size_t j = i - 6291456, layer = j / 2097152, off = j % 2097152;
        s = (const float4*)w1 + layer * 2097152 + off;
        didx = layer * 4194304 + 1048576 + off;
    } else {                                 // w2: 6 x 1048576
        size_t j = i - 18874368, layer = j / 1048576, off = j % 1048576;
        s = (const float4*)w2 + layer * 1048576 + off;
        didx = layer * 4194304 + 3145728 + off;
    }
    float4 v = *s;
    ushort4 o;
    o.x = f2bf(v.x); o.y = f2bf(v.y); o.z = f2bf(v.z); o.w = f2bf(v.w);
    ((ushort4*)dst)[didx] = o;
}

// ---------------- RMSNorm: fp32 in -> bf16 out ----------------
__global__ __launch_bounds__(256) void rmsnorm_bf(
        const float* __restrict__ x, const float* __restrict__ w,
        unsigned short* __restrict__ out) {
    __shared__ float sred[4];
    int row = blockIdx.x;
    int t = threadIdx.x;
    float4 v = ((const float4*)(x + (size_t)row * 1024))[t];
    float ss = v.x*v.x + v.y*v.y + v.z*v.z + v.w*v.w;
#pragma unroll
    for (int m = 32; m >= 1; m >>= 1) ss += __shfl_xor(ss, m, 64);
    if ((t & 63) == 0) sred[t >> 6] = ss;
    __syncthreads();
    float tot = sred[0] + sred[1] + sred[2] + sred[3];
    float r = rsqrtf(tot * (1.0f / 1024.0f) + 1e-6f);
    float4 wv = ((const float4*)w)[t];
    ushort4 o;
    o.x = f2bf(v.x * r * wv.x); o.y = f2bf(v.y * r * wv.y);
    o.z = f2bf(v.z * r * wv.z); o.w = f2bf(v.w * r * wv.w);
    ((ushort4*)(out + (size_t)row * 1024))[t] = o;
}

// ---------------- generic GEMM: C = A * W^T, split-K atomic fp32 out ----------------
// 128x128 tile, BK=32, 256 thr = 4 waves (2x2 of 64x64)
__global__ __launch_bounds__(256) void gemm_atomic(
        const unsigned short* __restrict__ A, const unsigned short* __restrict__ W,
        float* __restrict__ Cout, int Ncols, int Kd) {
    __shared__ __align__(16) unsigned short As[128 * 32];
    __shared__ __align__(16) unsigned short Bs[128 * 32];
    int t = threadIdx.x;
    int wave = t >> 6, lane = t & 63;
    int wm = wave >> 1, wn = wave & 1;
    int lrow = lane & 15, quad = lane >> 4;
    int bmBase = blockIdx.y * 128, bnBase = blockIdx.x * 128;
    int kslice = Kd / gridDim.z;
    int kBeg = blockIdx.z * kslice, kEnd = kBeg + kslice;
    int sub = lane >> 2, colb = (lane & 3) * 8;
    int c0 = wave, c1 = wave + 4;

    floatx4 acc[4][4] = {};

    for (int k0 = kBeg; k0 < kEnd; k0 += 32) {
        async16(&As[c0 * 512 + lane * 8], A + (size_t)(bmBase + c0 * 16 + sub) * Kd + k0 + colb);
        async16(&As[c1 * 512 + lane * 8], A + (size_t)(bmBase + c1 * 16 + sub) * Kd + k0 + colb);
        async16(&Bs[c0 * 512 + lane * 8], W + (size_t)(bnBase + c0 * 16 + sub) * Kd + k0 + colb);
        async16(&Bs[c1 * 512 + lane * 8], W + (size_t)(bnBase + c1 * 16 + sub) * Kd + k0 + colb);
        __syncthreads();
        bf16x8 af[4], bfr[4];
#pragma unroll
        for (int im = 0; im < 4; im++)
            af[im] = *(const bf16x8*)&As[(wm * 64 + im * 16 + lrow) * 32 + quad * 8];
#pragma unroll
        for (int in = 0; in < 4; in++)
            bfr[in] = *(const bf16x8*)&Bs[(wn * 64 + in * 16 + lrow) * 32 + quad * 8];
#pragma unroll
        for (int im = 0; im < 4; im++)
#pragma unroll
            for (int in = 0; in < 4; in++)
                acc[im][in] = __builtin_amdgcn_mfma_f32_16x16x32_bf16(af[im], bfr[in], acc[im][in], 0, 0, 0);
        __syncthreads();
    }

#pragma unroll
    for (int im = 0; im < 4; im++) {
        int gr0 = bmBase + wm * 64 + im * 16 + quad * 4;
#pragma unroll
        for (int in = 0; in < 4; in++) {
            int gc = bnBase + wn * 64 + in * 16 + lrow;
#pragma unroll
            for (int r2 = 0; r2 < 4; r2++)
                atomicAdd(Cout + (size_t)(gr0 + r2) * Ncols + gc, acc[im][in][r2]);
        }
    }
}

// ---------------- qkv GEMM with fused RoPE + V-transpose epilogue ----------------
// grid (24,16): x = n-tile over 3072 cols (q|k|v regions), y = m-tile over 2048 rows
__global__ __launch_bounds__(256) void gemm_qkv(
        const unsigned short* __restrict__ A, const unsigned short* __restrict__ W,
        unsigned short* __restrict__ qout, unsigned short* __restrict__ kout,
        unsigned short* __restrict__ vtout) {
    __shared__ __align__(16) unsigned short As[128 * 32];
    __shared__ __align__(16) unsigned short Bs[128 * 32];
    const int Kd = 1024;
    int t = threadIdx.x;
    int wave = t >> 6, lane = t & 63;
    int wm = wave >> 1, wn = wave & 1;
    int lrow = lane & 15, quad = lane >> 4;
    int bmBase = blockIdx.y * 128, bnBase = blockIdx.x * 128;
    int sub = lane >> 2, colb = (lane & 3) * 8;
    int c0 = wave, c1 = wave + 4;

    floatx4 acc[4][4] = {};

    for (int k0 = 0; k0 < Kd; k0 += 32) {
        async16(&As[c0 * 512 + lane * 8], A + (size_t)(bmBase + c0 * 16 + sub) * Kd + k0 + colb);
        async16(&As[c1 * 512 + lane * 8], A + (size_t)(bmBase + c1 * 16 + sub) * Kd + k0 + colb);
        async16(&Bs[c0 * 512 + lane * 8], W + (size_t)(bnBase + c0 * 16 + sub) * Kd + k0 + colb);
        async16(&Bs[c1 * 512 + lane * 8], W + (size_t)(bnBase + c1 * 16 + sub) * Kd + k0 + colb);
        __syncthreads();
        bf16x8 af[4], bfr[4];
#pragma unroll
        for (int im = 0; im < 4; im++)
            af[im] = *(const bf16x8*)&As[(wm * 64 + im * 16 + lrow) * 32 + quad * 8];
#pragma unroll
        for (int in = 0; in < 4; in++)
            bfr[in] = *(const bf16x8*)&Bs[(wn * 64 + in * 16 + lrow) * 32 + quad * 8];
#pragma unroll
        for (int im = 0; im < 4; im++)
#pragma unroll
            for (int in = 0; in < 4; in++)
                acc[im][in] = __builtin_amdgcn_mfma_f32_16x16x32_bf16(af[im], bfr[in], acc[im][in], 0, 0, 0);
        __syncthreads();
    }

    int region = bnBase >> 10;          // 0=q 1=k 2=v
    int cb = bnBase & 1023;
    int headbase = cb + wn * 64;        // head-aligned (mult of 64)
    if (region < 2) {
        unsigned short* dst = (region == 0) ? qout : kout;
        // rotate-half partner of col j is col j+32 = acc index in+2
#pragma unroll
        for (int in = 0; in < 2; in++) {
            int j = in * 16 + lrow;     // 0..31
            float invf = exp2f(-(float)j * (13.2877123795494f / 32.0f));  // 10000^{-j/32}
#pragma unroll
            for (int im = 0; im < 4; im++) {
                int n0 = bmBase + wm * 64 + im * 16 + quad * 4;
#pragma unroll
                for (int r2 = 0; r2 < 4; r2++) {
                    int n = n0 + r2;
                    float ang = (float)n * invf;
                    float s = sinf(ang), c = cosf(ang);
                    float x1 = acc[im][in][r2], x2 = acc[im][in + 2][r2];
                    dst[(size_t)n * 1024 + headbase + j]      = f2bf(x1 * c - x2 * s);
                    dst[(size_t)n * 1024 + headbase + j + 32] = f2bf(x2 * c + x1 * s);
                }
            }
        }
    } else {
#pragma unroll
        for (int im = 0; im < 4; im++) {
            int n0 = bmBase + wm * 64 + im * 16 + quad * 4;
#pragma unroll
            for (int in = 0; in < 4; in++) {
                int d = headbase + in * 16 + lrow;
                ushort4 o;
                o.x = f2bf(acc[im][in][0]); o.y = f2bf(acc[im][in][1]);
                o.z = f2bf(acc[im][in][2]); o.w = f2bf(acc[im][in][3]);
                *(ushort4*)&vtout[(size_t)d * 2048 + n0] = o;
            }
        }
    }
}

// ---------------- w1 GEMM with fused SiLU-gate epilogue ----------------
// grid (32,16): x = 128-col tile of the 4096 gate cols; block also computes the
// matching up-tile (cols +4096). Writes g = silu(a1)*a2 bf16 [2048,4096].
__global__ __launch_bounds__(256) void gemm_w1silu(
        const unsigned short* __restrict__ A, const unsigned short* __restrict__ W,
        unsigned short* __restrict__ g) {
    __shared__ __align__(16) unsigned short As[128 * 32];
    __shared__ __align__(16) unsigned short Bg[128 * 32];
    __shared__ __align__(16) unsigned short Bu[128 * 32];
    const int Kd = 1024;
    int t = threadIdx.x;
    int wave = t >> 6, lane = t & 63;
    int wm = wave >> 1, wn = wave & 1;
    int lrow = lane & 15, quad = lane >> 4;
    int bmBase = blockIdx.y * 128, bnBase = blockIdx.x * 128;
    int sub = lane >> 2, colb = (lane & 3) * 8;
    int c0 = wave, c1 = wave + 4;

    floatx4 accg[4][4] = {};
    floatx4 accu[4][4] = {};

    for (int k0 = 0; k0 < Kd; k0 += 32) {
        async16(&As[c0 * 512 + lane * 8], A + (size_t)(bmBase + c0 * 16 + sub) * Kd + k0 + colb);
        async16(&As[c1 * 512 + lane * 8], A + (size_t)(bmBase + c1 * 16 + sub) * Kd + k0 + colb);
        async16(&Bg[c0 * 512 + lane * 8], W + (size_t)(bnBase + c0 * 16 + sub) * Kd + k0 + colb);
        async16(&Bg[c1 * 512 + lane * 8], W + (size_t)(bnBase + c1 * 16 + sub) * Kd + k0 + colb);
        async16(&Bu[c0 * 512 + lane * 8], W + (size_t)(4096 + bnBase + c0 * 16 + sub) * Kd + k0 + colb);
        async16(&Bu[c1 * 512 + lane * 8], W + (size_t)(4096 + bnBase + c1 * 16 + sub) * Kd + k0 + colb);
        __syncthreads();
        bf16x8 af[4], bg[4], bu[4];
#pragma unroll
        for (int im = 0; im < 4; im++)
            af[im] = *(const bf16x8*)&As[(wm * 64 + im * 16 + lrow) * 32 + quad * 8];
#pragma unroll
        for (int in = 0; in < 4; in++) {
            bg[in] = *(const bf16x8*)&Bg[(wn * 64 + in * 16 + lrow) * 32 + quad * 8];
            bu[in] = *(const bf16x8*)&Bu[(wn * 64 + in * 16 + lrow) * 32 + quad * 8];
        }
#pragma unroll
        for (int im = 0; im < 4; im++)
#pragma unroll
            for (int in = 0; in < 4; in++) {
                accg[im][in] = __builtin_amdgcn_mfma_f32_16x16x32_bf16(af[im], bg[in], accg[im][in], 0, 0, 0);
                accu[im][in] = __builtin_amdgcn_mfma_f32_16x16x32_bf16(af[im], bu[in], accu[im][in], 0, 0, 0);
            }
        __syncthreads();
    }

#pragma unroll
    for (int im = 0; im < 4; im++) {
        int gr0 = bmBase + wm * 64 + im * 16 + quad * 4;
#pragma unroll
        for (int in = 0; in < 4; in++) {
            int gc = bnBase + wn * 64 + in * 16 + lrow;
#pragma unroll
            for (int r2 = 0; r2 < 4; r2++) {
                float a1 = accg[im][in][r2], a2 = accu[im][in][r2];
                float gv = a1 / (1.0f + __expf(-a1)) * a2;
                g[(size_t)(gr0 + r2) * 4096 + gc] = f2bf(gv);
            }
        }
    }
}

// ---------------- Flash attention (causal), bf16 in/out ----------------
__global__ __launch_bounds__(256) void attn_bf(
        const unsigned short* __restrict__ q, const unsigned short* __restrict__ kbuf,
        const unsigned short* __restrict__ vt, unsigned short* __restrict__ attn) {
    __shared__ __align__(16) unsigned short Qs[64 * 64];
    __shared__ __align__(16) unsigned short Ks[64 * 64];
    __shared__ __align__(16) unsigned short Vs[64 * 64];   // [dim][key]
    __shared__ __align__(16) unsigned short Ps[4 * 16 * 64];
    int qb = blockIdx.x;
    int h  = blockIdx.y;
    int t = threadIdx.x;
    int wave = t >> 6, lane = t & 63;
    int lrow = lane & 15, quad = lane >> 4;
    int sub8 = lane >> 3, col8 = (lane & 7) * 8;
    int c0 = wave, c1 = wave + 4;

    async16(&Qs[c0 * 512 + lane * 8], q + (size_t)(qb * 64 + c0 * 8 + sub8) * 1024 + h * 64 + col8);
    async16(&Qs[c1 * 512 + lane * 8], q + (size_t)(qb * 64 + c1 * 8 + sub8) * 1024 + h * 64 + col8);

    floatx4 oacc[4] = {};
    float mrow[4], lsum[4];
#pragma unroll
    for (int r2 = 0; r2 < 4; r2++) { mrow[r2] = -INFINITY; lsum[r2] = 0.0f; }

    for (int kt = 0; kt <= qb; ++kt) {
        __syncthreads();
        async16(&Ks[c0 * 512 + lane * 8], kbuf + (size_t)(kt * 64 + c0 * 8 + sub8) * 1024 + h * 64 + col8);
        async16(&Ks[c1 * 512 + lane * 8], kbuf + (size_t)(kt * 64 + c1 * 8 + sub8) * 1024 + h * 64 + col8);
        async16(&Vs[c0 * 512 + lane * 8], vt + (size_t)(h * 64 + c0 * 8 + sub8) * 2048 + kt * 64 + col8);
        async16(&Vs[c1 * 512 + lane * 8], vt + (size_t)(h * 64 + c1 * 8 + sub8) * 2048 + kt * 64 + col8);
        __syncthreads();

        floatx4 sacc[4] = {};
#pragma unroll
        for (int kk = 0; kk < 64; kk += 32) {
            bf16x8 aq = *(const bf16x8*)&Qs[(wave * 16 + lrow) * 64 + kk + quad * 8];
#pragma unroll
            for (int jn = 0; jn < 4; jn++) {
                bf16x8 bk = *(const bf16x8*)&Ks[(jn * 16 + lrow) * 64 + kk + quad * 8];
                sacc[jn] = __builtin_amdgcn_mfma_f32_16x16x32_bf16(aq, bk, sacc[jn], 0, 0, 0);
            }
        }

#pragma unroll
        for (int r2 = 0; r2 < 4; r2++) {
            int qg = qb * 64 + wave * 16 + quad * 4 + r2;
            float sv[4];
            float rm = -INFINITY;
#pragma unroll
            for (int jn = 0; jn < 4; jn++) {
                float xv = sacc[jn][r2] * 0.125f;
                int kg = kt * 64 + jn * 16 + lrow;
                if (kg > qg) xv = -INFINITY;
                sv[jn] = xv;
                rm = fmaxf(rm, xv);
            }
#pragma unroll
            for (int m = 8; m >= 1; m >>= 1) rm = fmaxf(rm, __shfl_xor(rm, m, 64));
            float mnew = fmaxf(mrow[r2], rm);
            float alpha = __expf(mrow[r2] - mnew);
            float rs = 0.0f;
#pragma unroll
            for (int jn = 0; jn < 4; jn++) {
                float p = __expf(sv[jn] - mnew);
                rs += p;
                Ps[wave * 1024 + (quad * 4 + r2) * 64 + jn * 16 + lrow] = f2bf(p);
            }
#pragma unroll
            for (int m = 8; m >= 1; m >>= 1) rs += __shfl_xor(rs, m, 64);
            lsum[r2] = lsum[r2] * alpha + rs;
            mrow[r2] = mnew;
#pragma unroll
            for (int jd = 0; jd < 4; jd++) oacc[jd][r2] *= alpha;
        }
        __syncthreads();

#pragma unroll
        for (int kk = 0; kk < 64; kk += 32) {
            bf16x8 ap = *(const bf16x8*)&Ps[wave * 1024 + lrow * 64 + kk + quad * 8];
#pragma unroll
            for (int jd = 0; jd < 4; jd++) {
                bf16x8 bv = *(const bf16x8*)&Vs[(jd * 16 + lrow) * 64 + kk + quad * 8];
                oacc[jd] = __builtin_amdgcn_mfma_f32_16x16x32_bf16(ap, bv, oacc[jd], 0, 0, 0);
            }
        }
    }

#pragma unroll
    for (int r2 = 0; r2 < 4; r2++) {
        int qg = qb * 64 + wave * 16 + quad * 4 + r2;
        float invl = 1.0f / lsum[r2];
#pragma unroll
        for (int jd = 0; jd < 4; jd++)
            attn[(size_t)qg * 1024 + h * 64 + jd * 16 + lrow] = f2bf(oacc[jd][r2] * invl);
    }
}

// ---------------- launch ----------------
extern "C" void kernel_launch(void* const* d_in, const int* in_sizes, int n_in,
                              void* d_out, int out_size, void* d_ws, size_t ws_size,
                              hipStream_t stream) {
    const float* x     = (const float*)d_in[0];
    const float* qkv_w = (const float*)d_in[1];
    const float* out_w = (const float*)d_in[2];
    const float* w1    = (const float*)d_in[3];
    const float* w2    = (const float*)d_in[4];
    const float* n1    = (const float*)d_in[5];
    const float* n2    = (const float*)d_in[6];

    char* ws = (char*)d_ws;
    float*          xbuf  = (float*)ws;                         // 8 MB
    unsigned short* hbuf  = (unsigned short*)(ws + 8388608);    // 4 MB
    unsigned short* qb_   = (unsigned short*)(ws + 12582912);   // 4 MB
    unsigned short* kb_   = (unsigned short*)(ws + 16777216);   // 4 MB
    unsigned short* vtb   = (unsigned short*)(ws + 20971520);   // 4 MB
    unsigned short* attnb = (unsigned short*)(ws + 25165824);   // 4 MB
    unsigned short* gbuf  = (unsigned short*)(ws + 29360128);   // 16 MB
    unsigned short* wslot = (unsigned short*)(ws + 46137344);   // 201.3 MB (6 layers bf16)

    hipMemcpyAsync(xbuf, x, (size_t)2048 * 1024 * 4, hipMemcpyDeviceToDevice, stream);
    conv_all<<<98304, 256, 0, stream>>>(qkv_w, out_w, w1, w2, wslot);

    for (int i = 0; i < 6; i++) {
        unsigned short* wb = wslot + (size_t)i * 16777216;
        unsigned short* qkvw = wb;
        unsigned short* outw = wb + 3145728;
        unsigned short* w1w  = wb + 4194304;
        unsigned short* w2w  = wb + 12582912;

        rmsnorm_bf<<<2048, 256, 0, stream>>>(xbuf, n1 + (size_t)i * 1024, hbuf);
        gemm_qkv<<<dim3(24, 16), 256, 0, stream>>>(hbuf, qkvw, qb_, kb_, vtb);
        attn_bf<<<dim3(32, 16), 256, 0, stream>>>(qb_, kb_, vtb, attnb);
        gemm_atomic<<<dim3(8, 16, 2), 256, 0, stream>>>(attnb, outw, xbuf, 1024, 1024);
        rmsnorm_bf<<<2048, 256, 0, stream>>>(xbuf, n2 + (size_t)i * 1024, hbuf);
        gemm_w1silu<<<dim3(32, 16), 256, 0, stream>>>(hbuf, w1w, gbuf);
        gemm_atomic<<<dim3(8, 16, 4), 256, 0, stream>>>(gbuf, w2w, xbuf, 1024, 4096);
    }

    hipMemcpyAsync(d_out, xbuf, (size_t)2048 * 1024 * 4, hipMemcpyDeviceToDevice, stream);
}